// Round 1
// baseline (595.995 us; speedup 1.0000x reference)
//
#include <hip/hip_runtime.h>
#include <hip/hip_bf16.h>
#include <cstdint>

#define BN_SCALEF 0.99999500003749975f  // 1/sqrt(1+1e-5)

// Problem constants
// B=128, N=200, F=768, H=8, Fo=32, Fh=256

// ---------------------------------------------------------------- prep kernels

__global__ void pack_mask(const int* __restrict__ adj, unsigned int* __restrict__ maskw) {
    int bi = blockIdx.x;            // b*200 + i, 25600 blocks
    int t  = threadIdx.x;           // 256
    bool v = false;
    if (t < 200) v = adj[(size_t)bi * 200 + t] > 0;
    unsigned long long m = __ballot(v ? 1 : 0);
    if ((t & 63) == 0) {
        maskw[bi * 8 + (t >> 6) * 2 + 0] = (unsigned int)(m & 0xffffffffULL);
        maskw[bi * 8 + (t >> 6) * 2 + 1] = (unsigned int)(m >> 32);
    }
}

__global__ void build_wcat(const float* __restrict__ W_heads, float* __restrict__ Wcat) {
    int f = blockIdx.x;   // 768
    int c = threadIdx.x;  // 256
    // Wcat[f][c] with c = h*32+o ; W_heads [H][F][Fo]
    Wcat[f * 256 + c] = W_heads[(c >> 5) * (768 * 32) + f * 32 + (c & 31)];
}

__global__ void build_w2t(const float* __restrict__ Ws, const float* __restrict__ Wp,
                          const float* __restrict__ Wq, float* __restrict__ W2t) {
    int c = blockIdx.x;   // 36
    int k = threadIdx.x;  // 256
    float v;
    if (c < 2)      v = Ws[k * 2 + c];
    else if (c < 4) v = Wp[k * 2 + (c - 2)];
    else            v = Wq[k * 32 + (c - 4)];
    W2t[c * 256 + k] = v;
}

// ---------------------------------------------------------------- GEMM1: h_all = feat @ Wcat
// A [25600][768] * B [768][256] -> C [25600][256]; 32x256 tile, 256 thr, 4x8 micro

__global__ __launch_bounds__(256) void gemm1(const float* __restrict__ A,
                                             const float* __restrict__ Bm,
                                             float* __restrict__ C) {
    __shared__ __align__(16) float As[16 * 32];
    __shared__ __align__(16) float Bs[16 * 256];
    int t  = threadIdx.x;
    int m0 = blockIdx.x * 32;
    int tx = t & 31, ty = t >> 5;          // tx: 8-col group, ty: 4-row group
    float acc[4][8] = {};
    for (int k0 = 0; k0 < 768; k0 += 16) {
        if (t < 128) {
            int r = t >> 2, w = t & 3;
            float4 v = *(const float4*)&A[(size_t)(m0 + r) * 768 + k0 + w * 4];
            As[(w * 4 + 0) * 32 + r] = v.x;
            As[(w * 4 + 1) * 32 + r] = v.y;
            As[(w * 4 + 2) * 32 + r] = v.z;
            As[(w * 4 + 3) * 32 + r] = v.w;
        }
#pragma unroll
        for (int rep = 0; rep < 4; ++rep) {
            int idx = rep * 256 + t;
            int kk = idx >> 6, cc = (idx & 63) * 4;
            *(float4*)&Bs[kk * 256 + cc] = *(const float4*)&Bm[(size_t)(k0 + kk) * 256 + cc];
        }
        __syncthreads();
#pragma unroll
        for (int kk = 0; kk < 16; ++kk) {
            float4 av = *(float4*)&As[kk * 32 + ty * 4];
            float4 b0 = *(float4*)&Bs[kk * 256 + tx * 8];
            float4 b1 = *(float4*)&Bs[kk * 256 + tx * 8 + 4];
            float a_[4] = {av.x, av.y, av.z, av.w};
            float b_[8] = {b0.x, b0.y, b0.z, b0.w, b1.x, b1.y, b1.z, b1.w};
#pragma unroll
            for (int i = 0; i < 4; ++i)
#pragma unroll
                for (int j = 0; j < 8; ++j) acc[i][j] += a_[i] * b_[j];
        }
        __syncthreads();
    }
#pragma unroll
    for (int i = 0; i < 4; ++i) {
        float4 o0 = {acc[i][0], acc[i][1], acc[i][2], acc[i][3]};
        float4 o1 = {acc[i][4], acc[i][5], acc[i][6], acc[i][7]};
        size_t base = (size_t)(m0 + ty * 4 + i) * 256 + tx * 8;
        *(float4*)&C[base]     = o0;
        *(float4*)&C[base + 4] = o1;
    }
}

// ---------------------------------------------------------------- s1/s2 per head

__global__ __launch_bounds__(256) void s12_heads(const float* __restrict__ h_all,
                                                 const float* __restrict__ a_heads,
                                                 float* __restrict__ s1, float* __restrict__ s2) {
    int t  = blockIdx.x * 256 + threadIdx.x;  // 204800
    int h  = t & 7;
    int bn = t >> 3;                          // [0, 25600)
    const float* hp = &h_all[(size_t)bn * 256 + h * 32];
    const float* a1 = &a_heads[h * 64];
    float acc1 = 0.f, acc2 = 0.f;
#pragma unroll
    for (int w4 = 0; w4 < 32; w4 += 4) {
        float4 v = *(const float4*)&hp[w4];
        acc1 += v.x * a1[w4] + v.y * a1[w4 + 1] + v.z * a1[w4 + 2] + v.w * a1[w4 + 3];
        acc2 += v.x * a1[32 + w4] + v.y * a1[33 + w4] + v.z * a1[34 + w4] + v.w * a1[35 + w4];
    }
    s1[h * 25600 + bn] = acc1;
    s2[h * 25600 + bn] = acc2;
}

// ---------------------------------------------------------------- head attention (fused softmax + att@h + BN + ELU + top BN)
// grid 1024 = (h,b); 256 thr = 4 waves; wave processes groups of 8 rows

__global__ __launch_bounds__(256) void attn_heads(
    const float* __restrict__ h_all, const float* __restrict__ s1g, const float* __restrict__ s2g,
    const unsigned int* __restrict__ maskw,
    const float* __restrict__ bnh_g, const float* __restrict__ bnh_b,
    const float* __restrict__ bnt_g, const float* __restrict__ bnt_b,
    float* __restrict__ x_cat) {
    __shared__ __align__(16) float h_t[32 * 204];       // [o][j], stride 204
    __shared__ __align__(16) float p_buf[4][8][204];    // [wave][row][j]
    __shared__ float s2s[200];
    int hb = blockIdx.x;
    int h = hb >> 7, b = hb & 127;
    int t = threadIdx.x;
    for (int idx = t; idx < 1600; idx += 256) {
        int j = idx >> 3, w4 = (idx & 7) * 4;
        float4 v = *(const float4*)&h_all[(size_t)(b * 200 + j) * 256 + h * 32 + w4];
        h_t[(w4 + 0) * 204 + j] = v.x;
        h_t[(w4 + 1) * 204 + j] = v.y;
        h_t[(w4 + 2) * 204 + j] = v.z;
        h_t[(w4 + 3) * 204 + j] = v.w;
    }
    if (t < 200) s2s[t] = s2g[(h * 128 + b) * 200 + t];
    __syncthreads();

    int w = t >> 6, lane = t & 63;
    int o = lane & 31, gg = lane >> 5;
    for (int grp = w; grp < 25; grp += 4) {
        int i0 = grp * 8;
        float invd[8];
#pragma unroll
        for (int r = 0; r < 8; ++r) {
            int i = i0 + r;
            float s1v = s1g[(h * 128 + b) * 200 + i];
            float e[4];
            bool val[4];
            float mx = -3.0e38f;
#pragma unroll
            for (int q = 0; q < 4; ++q) {
                int j = lane + 64 * q;
                bool vv = false;
                float ev = -3.0e38f;
                if (j < 200) {
                    unsigned int mw = maskw[(size_t)(b * 200 + i) * 8 + (j >> 5)];
                    vv = (mw >> (j & 31)) & 1u;
                    if (vv) {
                        float x = s1v + s2s[j];
                        ev = x >= 0.f ? x : 0.3f * x;
                        mx = fmaxf(mx, ev);
                    }
                }
                val[q] = vv;
                e[q] = ev;
            }
            for (int off = 32; off; off >>= 1) mx = fmaxf(mx, __shfl_xor(mx, off, 64));
            float dsum = 0.f;
#pragma unroll
            for (int q = 0; q < 4; ++q) {
                int j = lane + 64 * q;
                float p = val[q] ? __expf(e[q] - mx) : 0.f;
                if (j < 200) p_buf[w][r][j] = p;
                dsum += p;
            }
            for (int off = 32; off; off >>= 1) dsum += __shfl_xor(dsum, off, 64);
            invd[r] = 1.f / dsum;
        }
        __threadfence_block();  // cross-lane LDS visibility within the wave

        float acc[8] = {};
        for (int cc = gg; cc < 50; cc += 2) {
            int jb = cc * 4;
            float4 hv = *(float4*)&h_t[o * 204 + jb];
#pragma unroll
            for (int r = 0; r < 8; ++r) {
                float4 pv = *(float4*)&p_buf[w][r][jb];
                acc[r] += hv.x * pv.x + hv.y * pv.y + hv.z * pv.z + hv.w * pv.w;
            }
        }
#pragma unroll
        for (int r = 0; r < 8; ++r) acc[r] += __shfl_xor(acc[r], 32, 64);
        if (lane < 32) {
#pragma unroll
            for (int r = 0; r < 8; ++r) {
                int i = i0 + r;
                float hp = acc[r] * invd[r];
                float v = hp * (BN_SCALEF * bnh_g[h * 200 + i]) + bnh_b[h * 200 + i];
                v = v > 0.f ? v : __expf(v) - 1.f;                       // ELU (concat=True)
                v = v * (BN_SCALEF * bnt_g[i]) + bnt_b[i];               // top-level BN
                x_cat[(size_t)(b * 200 + i) * 256 + h * 32 + o] = v;
            }
        }
        __threadfence_block();
    }
}

// ---------------------------------------------------------------- GEMM2: h2 = x_cat @ W2t^T  (36 cols)

__global__ __launch_bounds__(256) void gemm2(const float* __restrict__ X,
                                             const float* __restrict__ W2t,
                                             float* __restrict__ H2) {
    __shared__ __align__(16) float Ws[36 * 260];
    int t = threadIdx.x;
#pragma unroll
    for (int rep = 0; rep < 9; ++rep) {
        int fidx = rep * 1024 + t * 4;
        int c = fidx >> 8, k = fidx & 255;
        *(float4*)&Ws[c * 260 + k] = *(const float4*)&W2t[fidx];
    }
    __syncthreads();
    int cg = t & 3, rt = t >> 2;
    int row0 = blockIdx.x * 128 + rt * 2;
    float acc[2][9] = {};
#pragma unroll 2
    for (int k = 0; k < 256; k += 4) {
        float4 x0 = *(const float4*)&X[(size_t)row0 * 256 + k];
        float4 x1 = *(const float4*)&X[(size_t)(row0 + 1) * 256 + k];
#pragma unroll
        for (int c = 0; c < 9; ++c) {
            float4 wv = *(float4*)&Ws[(cg * 9 + c) * 260 + k];
            acc[0][c] += x0.x * wv.x + x0.y * wv.y + x0.z * wv.z + x0.w * wv.w;
            acc[1][c] += x1.x * wv.x + x1.y * wv.y + x1.z * wv.z + x1.w * wv.w;
        }
    }
#pragma unroll
    for (int rr = 0; rr < 2; ++rr)
#pragma unroll
        for (int c = 0; c < 9; ++c)
            H2[(size_t)(row0 + rr) * 36 + cg * 9 + c] = acc[rr][c];
}

// ---------------------------------------------------------------- s1/s2 for sent/para/q

__global__ __launch_bounds__(256) void s12_second(const float* __restrict__ H2,
                                                  const float* __restrict__ a_sent,
                                                  const float* __restrict__ a_para,
                                                  const float* __restrict__ a_q,
                                                  float* __restrict__ sv) {
    int row = blockIdx.x * 256 + threadIdx.x;  // 25600
    const float* hp = &H2[(size_t)row * 36];
    float h0 = hp[0], h1 = hp[1], h2v = hp[2], h3 = hp[3];
    sv[row]          = h0 * a_sent[0] + h1 * a_sent[1];
    sv[25600 + row]  = h0 * a_sent[2] + h1 * a_sent[3];
    sv[51200 + row]  = h2v * a_para[0] + h3 * a_para[1];
    sv[76800 + row]  = h2v * a_para[2] + h3 * a_para[3];
    float aq1 = 0.f, aq2 = 0.f;
#pragma unroll
    for (int o = 0; o < 32; ++o) {
        float hv = hp[4 + o];
        aq1 += hv * a_q[o];
        aq2 += hv * a_q[32 + o];
    }
    sv[102400 + row] = aq1;
    sv[128000 + row] = aq2;
}

// ---------------------------------------------------------------- sent+para attention (Fo=2 each), wave-per-row

__global__ __launch_bounds__(256) void attn_sp(const float* __restrict__ H2,
                                               const float* __restrict__ sv,
                                               const unsigned int* __restrict__ maskw,
                                               const float* __restrict__ bns_g, const float* __restrict__ bns_b,
                                               const float* __restrict__ bnp_g, const float* __restrict__ bnp_b,
                                               float* __restrict__ out) {
    __shared__ float s2s[200], s2p[200];
    __shared__ __align__(16) float hsp[200 * 4];
    int b = blockIdx.x, chunk = blockIdx.y;
    int t = threadIdx.x;
    if (t < 200) {
        s2s[t] = sv[25600 + b * 200 + t];
        s2p[t] = sv[76800 + b * 200 + t];
    }
    for (int idx = t; idx < 800; idx += 256) {
        int j = idx >> 2, c = idx & 3;
        hsp[idx] = H2[(size_t)(b * 200 + j) * 36 + c];
    }
    __syncthreads();
    int w = t >> 6, lane = t & 63;
    for (int it = 0; it < 25; ++it) {
        int i = chunk * 100 + it * 4 + w;
        float s1sv = sv[b * 200 + i];
        float s1pv = sv[51200 + b * 200 + i];
        float es[4], ep[4];
        bool val[4];
        float mxs = -3.0e38f, mxp = -3.0e38f;
#pragma unroll
        for (int q = 0; q < 4; ++q) {
            int j = lane + 64 * q;
            bool vv = false;
            float e1 = -3.0e38f, e2 = -3.0e38f;
            if (j < 200) {
                unsigned int mw = maskw[(size_t)(b * 200 + i) * 8 + (j >> 5)];
                vv = (mw >> (j & 31)) & 1u;
                if (vv) {
                    float x1 = s1sv + s2s[j]; e1 = x1 >= 0.f ? x1 : 0.3f * x1;
                    float x2 = s1pv + s2p[j]; e2 = x2 >= 0.f ? x2 : 0.3f * x2;
                    mxs = fmaxf(mxs, e1);
                    mxp = fmaxf(mxp, e2);
                }
            }
            val[q] = vv; es[q] = e1; ep[q] = e2;
        }
        for (int off = 32; off; off >>= 1) {
            mxs = fmaxf(mxs, __shfl_xor(mxs, off, 64));
            mxp = fmaxf(mxp, __shfl_xor(mxp, off, 64));
        }
        float ds = 0.f, dp = 0.f, pa0 = 0.f, pa1 = 0.f, pb0 = 0.f, pb1 = 0.f;
#pragma unroll
        for (int q = 0; q < 4; ++q) {
            if (!val[q]) continue;
            int j = lane + 64 * q;
            float p1 = __expf(es[q] - mxs), p2 = __expf(ep[q] - mxp);
            ds += p1; dp += p2;
            float4 hv = *(float4*)&hsp[j * 4];
            pa0 += p1 * hv.x; pa1 += p1 * hv.y;
            pb0 += p2 * hv.z; pb1 += p2 * hv.w;
        }
        for (int off = 32; off; off >>= 1) {
            ds  += __shfl_xor(ds, off, 64);  dp  += __shfl_xor(dp, off, 64);
            pa0 += __shfl_xor(pa0, off, 64); pa1 += __shfl_xor(pa1, off, 64);
            pb0 += __shfl_xor(pb0, off, 64); pb1 += __shfl_xor(pb1, off, 64);
        }
        if (lane == 0) {
            float gs = BN_SCALEF * bns_g[i], bs = bns_b[i];
            float v0 = (pa0 / ds) * gs + bs, v1 = (pa1 / ds) * gs + bs;
            out[(size_t)(b * 200 + i) * 2 + 0] = 1.f / (1.f + __expf(-v0));
            out[(size_t)(b * 200 + i) * 2 + 1] = 1.f / (1.f + __expf(-v1));
            float gp = BN_SCALEF * bnp_g[i], bp = bnp_b[i];
            float u0 = (pb0 / dp) * gp + bp, u1 = (pb1 / dp) * gp + bp;
            out[51200 + (size_t)(b * 200 + i) * 2 + 0] = u0 > 0.f ? u0 : __expf(u0) - 1.f;
            out[51200 + (size_t)(b * 200 + i) * 2 + 1] = u1 > 0.f ? u1 : __expf(u1) - 1.f;
        }
    }
}

// ---------------------------------------------------------------- q attention (row 0 only) + W2 + ELU

__global__ __launch_bounds__(256) void attn_q(const float* __restrict__ H2,
                                              const float* __restrict__ sv,
                                              const unsigned int* __restrict__ maskw,
                                              const float* __restrict__ bnq_g, const float* __restrict__ bnq_b,
                                              const float* __restrict__ W2, float* __restrict__ out) {
    __shared__ float p_lds[200];
    __shared__ float redm[4], redd[4];
    __shared__ float red2[256];
    int b = blockIdx.x, t = threadIdx.x;
    float s1v = sv[102400 + b * 200];
    bool v = false;
    float e = -3.0e38f;
    if (t < 200) {
        unsigned int mw = maskw[(size_t)(b * 200) * 8 + (t >> 5)];
        v = (mw >> (t & 31)) & 1u;
        if (v) {
            float x = s1v + sv[128000 + b * 200 + t];
            e = x >= 0.f ? x : 0.3f * x;
        }
    }
    float mx = e;
    for (int off = 32; off; off >>= 1) mx = fmaxf(mx, __shfl_xor(mx, off, 64));
    if ((t & 63) == 0) redm[t >> 6] = mx;
    __syncthreads();
    mx = fmaxf(fmaxf(redm[0], redm[1]), fmaxf(redm[2], redm[3]));
    float p = v ? __expf(e - mx) : 0.f;
    if (t < 200) p_lds[t] = p;
    float ds = p;
    for (int off = 32; off; off >>= 1) ds += __shfl_xor(ds, off, 64);
    if ((t & 63) == 0) redd[t >> 6] = ds;
    __syncthreads();
    ds = redd[0] + redd[1] + redd[2] + redd[3];
    int o = t & 31, g = t >> 5;
    float acc = 0.f;
    for (int j = g; j < 200; j += 8)
        acc += p_lds[j] * H2[(size_t)(b * 200 + j) * 36 + 4 + o];
    red2[t] = acc;
    __syncthreads();
    if (t < 32) {
        float s = 0.f;
#pragma unroll
        for (int gg = 0; gg < 8; ++gg) s += red2[gg * 32 + t];
        float qv = (s / ds) * (BN_SCALEF * bnq_g[0]) + bnq_b[0];  // node 0, no ELU (concat=False)
        float c0 = qv * W2[t * 2], c1 = qv * W2[t * 2 + 1];
#pragma unroll
        for (int off = 16; off; off >>= 1) {
            c0 += __shfl_xor(c0, off, 64);
            c1 += __shfl_xor(c1, off, 64);
        }
        if (t == 0) {
            out[102400 + b * 2 + 0] = c0 > 0.f ? c0 : __expf(c0) - 1.f;
            out[102400 + b * 2 + 1] = c1 > 0.f ? c1 : __expf(c1) - 1.f;
        }
    }
}

// ---------------------------------------------------------------- launch

extern "C" void kernel_launch(void* const* d_in, const int* in_sizes, int n_in,
                              void* d_out, int out_size, void* d_ws, size_t ws_size,
                              hipStream_t stream) {
    (void)in_sizes; (void)n_in; (void)out_size; (void)ws_size;
    const float* feat    = (const float*)d_in[0];
    const int*   adj     = (const int*)d_in[1];
    const float* W_heads = (const float*)d_in[2];
    const float* a_heads = (const float*)d_in[3];
    const float* bnh_g   = (const float*)d_in[4];
    const float* bnh_b   = (const float*)d_in[5];
    const float* bnt_g   = (const float*)d_in[6];
    const float* bnt_b   = (const float*)d_in[7];
    const float* W_sent  = (const float*)d_in[8];
    const float* a_sent  = (const float*)d_in[9];
    const float* bns_g   = (const float*)d_in[10];
    const float* bns_b   = (const float*)d_in[11];
    const float* W_para  = (const float*)d_in[12];
    const float* a_para  = (const float*)d_in[13];
    const float* bnp_g   = (const float*)d_in[14];
    const float* bnp_b   = (const float*)d_in[15];
    const float* W_q     = (const float*)d_in[16];
    const float* a_q     = (const float*)d_in[17];
    const float* bnq_g   = (const float*)d_in[18];
    const float* bnq_b   = (const float*)d_in[19];
    const float* W2      = (const float*)d_in[20];
    float* out = (float*)d_out;
    float* ws  = (float*)d_ws;

    float* h_all = ws;                        // 6,553,600 f
    float* x_cat = ws + 6553600;              // 6,553,600 f
    float* s1h   = ws + 13107200;             // 204,800 f
    float* s2h   = ws + 13312000;             // 204,800 f
    float* wcat  = ws + 13516800;             // 196,608 f
    float* w2t   = ws + 13713408;             // 9,216 f
    unsigned int* maskw = (unsigned int*)(ws + 13722624);  // 204,800 words
    float* h2    = ws + 13927424;             // 921,600 f
    float* sv    = ws + 14849024;             // 153,600 f  (end ~60 MB)

    pack_mask<<<dim3(25600), dim3(256), 0, stream>>>(adj, maskw);
    build_wcat<<<dim3(768), dim3(256), 0, stream>>>(W_heads, wcat);
    build_w2t<<<dim3(36), dim3(256), 0, stream>>>(W_sent, W_para, W_q, w2t);
    gemm1<<<dim3(800), dim3(256), 0, stream>>>(feat, wcat, h_all);
    s12_heads<<<dim3(800), dim3(256), 0, stream>>>(h_all, a_heads, s1h, s2h);
    attn_heads<<<dim3(1024), dim3(256), 0, stream>>>(h_all, s1h, s2h, maskw,
                                                     bnh_g, bnh_b, bnt_g, bnt_b, x_cat);
    gemm2<<<dim3(200), dim3(256), 0, stream>>>(x_cat, w2t, h2);
    s12_second<<<dim3(100), dim3(256), 0, stream>>>(h2, a_sent, a_para, a_q, sv);
    attn_sp<<<dim3(128, 2), dim3(256), 0, stream>>>(h2, sv, maskw, bns_g, bns_b,
                                                    bnp_g, bnp_b, out);
    attn_q<<<dim3(128), dim3(256), 0, stream>>>(h2, sv, maskw, bnq_g, bnq_b, W2, out);
}

// Round 2
// 455.873 us; speedup vs baseline: 1.3074x; 1.3074x over previous
//
#include <hip/hip_runtime.h>
#include <hip/hip_bf16.h>
#include <cstdint>

#define BN_SCALEF 0.99999500003749975f  // 1/sqrt(1+1e-5)

// Problem constants: B=128, N=200, F=768, H=8, Fo=32, Fh=256

typedef _Float16 half8 __attribute__((ext_vector_type(8)));
typedef float floatx4 __attribute__((ext_vector_type(4)));

// ---------------------------------------------------------------- prep kernels

__global__ void pack_mask(const int* __restrict__ adj, unsigned int* __restrict__ maskw) {
    int bi = blockIdx.x;            // b*200 + i, 25600 blocks
    int t  = threadIdx.x;           // 256
    bool v = false;
    if (t < 200) v = adj[(size_t)bi * 200 + t] > 0;
    unsigned long long m = __ballot(v ? 1 : 0);
    if ((t & 63) == 0) {
        maskw[bi * 8 + (t >> 6) * 2 + 0] = (unsigned int)(m & 0xffffffffULL);
        maskw[bi * 8 + (t >> 6) * 2 + 1] = (unsigned int)(m >> 32);
    }
}

// Wcat^T in f16: Bt[c][f], c = h*32+o
__global__ void build_wcat_t(const float* __restrict__ W_heads, _Float16* __restrict__ Bt) {
    int c = blockIdx.x;   // 256
    int h = c >> 5, o = c & 31;
    for (int f = threadIdx.x; f < 768; f += 256)
        Bt[(size_t)c * 768 + f] = (_Float16)W_heads[h * (768 * 32) + f * 32 + o];
}

__global__ void build_w2t(const float* __restrict__ Ws, const float* __restrict__ Wp,
                          const float* __restrict__ Wq, float* __restrict__ W2t) {
    int c = blockIdx.x;   // 36
    int k = threadIdx.x;  // 256
    float v;
    if (c < 2)      v = Ws[k * 2 + c];
    else if (c < 4) v = Wp[k * 2 + (c - 2)];
    else            v = Wq[k * 32 + (c - 4)];
    W2t[c * 256 + k] = v;
}

// ---------------------------------------------------------------- GEMM1 (f16 MFMA) + fused s1/s2
// C[25600,256] = A[25600,768] (fp32, cast in staging) @ Bt^T (f16 [256][768])
// tile 128x256, 512 thr = 8 waves (2x4), wave = 4x4 tiles of 16x16, BK=32

__global__ __launch_bounds__(512) void gemm1_mfma(const float* __restrict__ A,
                                                  const _Float16* __restrict__ Bt,
                                                  const float* __restrict__ a_h,
                                                  float* __restrict__ C,
                                                  float* __restrict__ s1,
                                                  float* __restrict__ s2) {
    __shared__ __align__(16) _Float16 As[128 * 40];   // [row][k], stride 40 (pad 8)
    __shared__ __align__(16) _Float16 Bs[256 * 40];   // [col][k], stride 40
    int t = threadIdx.x;
    int m0 = blockIdx.x * 128;
    int w = t >> 6, lane = t & 63;
    int wr = w >> 2, wc = w & 3;            // wave 2x4 over (row, col)
    int quad = lane >> 4, l16 = lane & 15;

    floatx4 acc[4][4];
#pragma unroll
    for (int i = 0; i < 4; ++i)
#pragma unroll
        for (int j = 0; j < 4; ++j) acc[i][j] = (floatx4){0.f, 0.f, 0.f, 0.f};

    int arow = t >> 2, akoff = (t & 3) * 8;      // A: 128 rows x 32 k
    int bcol = t >> 1, bkoff = (t & 1) * 16;     // B: 256 cols x 32 k
    const float*    Aptr = &A[(size_t)(m0 + arow) * 768 + akoff];
    const _Float16* Bptr = &Bt[(size_t)bcol * 768 + bkoff];

    float4 pa0 = *(const float4*)(Aptr);
    float4 pa1 = *(const float4*)(Aptr + 4);
    uint4  pb0 = *(const uint4*)(Bptr);
    uint4  pb1 = *(const uint4*)(Bptr + 8);

    for (int k0 = 0; k0 < 768; k0 += 32) {
        half8 ah;
        ah[0] = (_Float16)pa0.x; ah[1] = (_Float16)pa0.y;
        ah[2] = (_Float16)pa0.z; ah[3] = (_Float16)pa0.w;
        ah[4] = (_Float16)pa1.x; ah[5] = (_Float16)pa1.y;
        ah[6] = (_Float16)pa1.z; ah[7] = (_Float16)pa1.w;
        *(half8*)&As[arow * 40 + akoff] = ah;
        *(uint4*)&Bs[bcol * 40 + bkoff]     = pb0;
        *(uint4*)&Bs[bcol * 40 + bkoff + 8] = pb1;
        __syncthreads();
        if (k0 + 32 < 768) {   // prefetch next staging into regs, hidden behind MFMA
            pa0 = *(const float4*)(Aptr + k0 + 32);
            pa1 = *(const float4*)(Aptr + k0 + 36);
            pb0 = *(const uint4*)(Bptr + k0 + 32);
            pb1 = *(const uint4*)(Bptr + k0 + 40);
        }
        half8 af[4], bf[4];
#pragma unroll
        for (int rt = 0; rt < 4; ++rt)
            af[rt] = *(half8*)&As[(wr * 64 + rt * 16 + l16) * 40 + quad * 8];
#pragma unroll
        for (int ct = 0; ct < 4; ++ct)
            bf[ct] = *(half8*)&Bs[(wc * 64 + ct * 16 + l16) * 40 + quad * 8];
#pragma unroll
        for (int rt = 0; rt < 4; ++rt)
#pragma unroll
            for (int ct = 0; ct < 4; ++ct)
                acc[rt][ct] = __builtin_amdgcn_mfma_f32_16x16x32_f16(af[rt], bf[ct], acc[rt][ct], 0, 0, 0);
        __syncthreads();
    }

    // C store: row = rbase + rt*16 + quad*4 + r, col = cbase + ct*16 + l16
    int rbase = m0 + wr * 64;
    int cbase = wc * 64;
#pragma unroll
    for (int rt = 0; rt < 4; ++rt)
#pragma unroll
        for (int ct = 0; ct < 4; ++ct) {
            int gc = cbase + ct * 16 + l16;
#pragma unroll
            for (int r = 0; r < 4; ++r) {
                int gr = rbase + rt * 16 + quad * 4 + r;
                C[(size_t)gr * 256 + gc] = acc[rt][ct][r];
            }
        }
    // fused s1/s2: wave's 64 cols = heads 2*wc, 2*wc+1
#pragma unroll
    for (int hh = 0; hh < 2; ++hh) {
        int h0 = wc * 2 + hh;
        const float* ab = &a_h[h0 * 64];
        float a1l = ab[l16], a1h = ab[16 + l16];
        float a2l = ab[32 + l16], a2h = ab[48 + l16];
#pragma unroll
        for (int rt = 0; rt < 4; ++rt)
#pragma unroll
            for (int r = 0; r < 4; ++r) {
                float v0 = acc[rt][2 * hh][r], v1 = acc[rt][2 * hh + 1][r];
                float p1 = v0 * a1l + v1 * a1h;
                float p2 = v0 * a2l + v1 * a2h;
                p1 += __shfl_xor(p1, 1, 64); p1 += __shfl_xor(p1, 2, 64);
                p1 += __shfl_xor(p1, 4, 64); p1 += __shfl_xor(p1, 8, 64);
                p2 += __shfl_xor(p2, 1, 64); p2 += __shfl_xor(p2, 2, 64);
                p2 += __shfl_xor(p2, 4, 64); p2 += __shfl_xor(p2, 8, 64);
                if (l16 == 0) {
                    int gr = rbase + rt * 16 + quad * 4 + r;
                    s1[h0 * 25600 + gr] = p1;
                    s2[h0 * 25600 + gr] = p2;
                }
            }
    }
}

// ---------------------------------------------------------------- head attention (fused softmax + att@h + BN + ELU + top BN)

__global__ __launch_bounds__(256) void attn_heads(
    const float* __restrict__ h_all, const float* __restrict__ s1g, const float* __restrict__ s2g,
    const unsigned int* __restrict__ maskw,
    const float* __restrict__ bnh_g, const float* __restrict__ bnh_b,
    const float* __restrict__ bnt_g, const float* __restrict__ bnt_b,
    float* __restrict__ x_cat) {
    __shared__ __align__(16) float h_t[32 * 204];       // [o][j], stride 204
    __shared__ __align__(16) float p_buf[4][8][204];    // [wave][row][j]
    __shared__ float s2s[200];
    int hb = blockIdx.x;
    int h = hb >> 7, b = hb & 127;
    int t = threadIdx.x;
    for (int idx = t; idx < 1600; idx += 256) {
        int j = idx >> 3, w4 = (idx & 7) * 4;
        float4 v = *(const float4*)&h_all[(size_t)(b * 200 + j) * 256 + h * 32 + w4];
        h_t[(w4 + 0) * 204 + j] = v.x;
        h_t[(w4 + 1) * 204 + j] = v.y;
        h_t[(w4 + 2) * 204 + j] = v.z;
        h_t[(w4 + 3) * 204 + j] = v.w;
    }
    if (t < 200) s2s[t] = s2g[(h * 128 + b) * 200 + t];
    __syncthreads();

    int w = t >> 6, lane = t & 63;
    int o = lane & 31, gg = lane >> 5;
    for (int grp = w; grp < 25; grp += 4) {
        int i0 = grp * 8;
        float invd[8];
#pragma unroll
        for (int r = 0; r < 8; ++r) {
            int i = i0 + r;
            float s1v = s1g[(h * 128 + b) * 200 + i];
            float e[4];
            bool val[4];
            float mx = -3.0e38f;
#pragma unroll
            for (int q = 0; q < 4; ++q) {
                int j = lane + 64 * q;
                bool vv = false;
                float ev = -3.0e38f;
                if (j < 200) {
                    unsigned int mw = maskw[(size_t)(b * 200 + i) * 8 + (j >> 5)];
                    vv = (mw >> (j & 31)) & 1u;
                    if (vv) {
                        float x = s1v + s2s[j];
                        ev = x >= 0.f ? x : 0.3f * x;
                        mx = fmaxf(mx, ev);
                    }
                }
                val[q] = vv;
                e[q] = ev;
            }
            for (int off = 32; off; off >>= 1) mx = fmaxf(mx, __shfl_xor(mx, off, 64));
            float dsum = 0.f;
#pragma unroll
            for (int q = 0; q < 4; ++q) {
                int j = lane + 64 * q;
                float p = val[q] ? __expf(e[q] - mx) : 0.f;
                if (j < 200) p_buf[w][r][j] = p;
                dsum += p;
            }
            for (int off = 32; off; off >>= 1) dsum += __shfl_xor(dsum, off, 64);
            invd[r] = 1.f / dsum;
        }
        __threadfence_block();

        float acc[8] = {};
        for (int cc = gg; cc < 50; cc += 2) {
            int jb = cc * 4;
            float4 hv = *(float4*)&h_t[o * 204 + jb];
#pragma unroll
            for (int r = 0; r < 8; ++r) {
                float4 pv = *(float4*)&p_buf[w][r][jb];
                acc[r] += hv.x * pv.x + hv.y * pv.y + hv.z * pv.z + hv.w * pv.w;
            }
        }
#pragma unroll
        for (int r = 0; r < 8; ++r) acc[r] += __shfl_xor(acc[r], 32, 64);
        if (lane < 32) {
#pragma unroll
            for (int r = 0; r < 8; ++r) {
                int i = i0 + r;
                float hp = acc[r] * invd[r];
                float v = hp * (BN_SCALEF * bnh_g[h * 200 + i]) + bnh_b[h * 200 + i];
                v = v > 0.f ? v : __expf(v) - 1.f;                       // ELU (concat=True)
                v = v * (BN_SCALEF * bnt_g[i]) + bnt_b[i];               // top-level BN
                x_cat[(size_t)(b * 200 + i) * 256 + h * 32 + o] = v;
            }
        }
        __threadfence_block();
    }
}

// ---------------------------------------------------------------- GEMM2: h2 = x_cat @ W2t^T  (36 cols)

__global__ __launch_bounds__(256) void gemm2(const float* __restrict__ X,
                                             const float* __restrict__ W2t,
                                             float* __restrict__ H2) {
    __shared__ __align__(16) float Ws[36 * 260];
    int t = threadIdx.x;
#pragma unroll
    for (int rep = 0; rep < 9; ++rep) {
        int fidx = rep * 1024 + t * 4;
        int c = fidx >> 8, k = fidx & 255;
        *(float4*)&Ws[c * 260 + k] = *(const float4*)&W2t[fidx];
    }
    __syncthreads();
    int cg = t & 3, rt = t >> 2;
    int row0 = blockIdx.x * 128 + rt * 2;
    float acc[2][9] = {};
#pragma unroll 2
    for (int k = 0; k < 256; k += 4) {
        float4 x0 = *(const float4*)&X[(size_t)row0 * 256 + k];
        float4 x1 = *(const float4*)&X[(size_t)(row0 + 1) * 256 + k];
#pragma unroll
        for (int c = 0; c < 9; ++c) {
            float4 wv = *(float4*)&Ws[(cg * 9 + c) * 260 + k];
            acc[0][c] += x0.x * wv.x + x0.y * wv.y + x0.z * wv.z + x0.w * wv.w;
            acc[1][c] += x1.x * wv.x + x1.y * wv.y + x1.z * wv.z + x1.w * wv.w;
        }
    }
#pragma unroll
    for (int rr = 0; rr < 2; ++rr)
#pragma unroll
        for (int c = 0; c < 9; ++c)
            H2[(size_t)(row0 + rr) * 36 + cg * 9 + c] = acc[rr][c];
}

// ---------------------------------------------------------------- s1/s2 for sent/para/q

__global__ __launch_bounds__(256) void s12_second(const float* __restrict__ H2,
                                                  const float* __restrict__ a_sent,
                                                  const float* __restrict__ a_para,
                                                  const float* __restrict__ a_q,
                                                  float* __restrict__ sv) {
    int row = blockIdx.x * 256 + threadIdx.x;  // 25600
    const float* hp = &H2[(size_t)row * 36];
    float h0 = hp[0], h1 = hp[1], h2v = hp[2], h3 = hp[3];
    sv[row]          = h0 * a_sent[0] + h1 * a_sent[1];
    sv[25600 + row]  = h0 * a_sent[2] + h1 * a_sent[3];
    sv[51200 + row]  = h2v * a_para[0] + h3 * a_para[1];
    sv[76800 + row]  = h2v * a_para[2] + h3 * a_para[3];
    float aq1 = 0.f, aq2 = 0.f;
#pragma unroll
    for (int o = 0; o < 32; ++o) {
        float hv = hp[4 + o];
        aq1 += hv * a_q[o];
        aq2 += hv * a_q[32 + o];
    }
    sv[102400 + row] = aq1;
    sv[128000 + row] = aq2;
}

// ---------------------------------------------------------------- sent+para attention (Fo=2 each), wave-per-row

__global__ __launch_bounds__(256) void attn_sp(const float* __restrict__ H2,
                                               const float* __restrict__ sv,
                                               const unsigned int* __restrict__ maskw,
                                               const float* __restrict__ bns_g, const float* __restrict__ bns_b,
                                               const float* __restrict__ bnp_g, const float* __restrict__ bnp_b,
                                               float* __restrict__ out) {
    __shared__ float s2s[200], s2p[200];
    __shared__ __align__(16) float hsp[200 * 4];
    int b = blockIdx.x, chunk = blockIdx.y;
    int t = threadIdx.x;
    if (t < 200) {
        s2s[t] = sv[25600 + b * 200 + t];
        s2p[t] = sv[76800 + b * 200 + t];
    }
    for (int idx = t; idx < 800; idx += 256) {
        int j = idx >> 2, c = idx & 3;
        hsp[idx] = H2[(size_t)(b * 200 + j) * 36 + c];
    }
    __syncthreads();
    int w = t >> 6, lane = t & 63;
    for (int it = 0; it < 25; ++it) {
        int i = chunk * 100 + it * 4 + w;
        float s1sv = sv[b * 200 + i];
        float s1pv = sv[51200 + b * 200 + i];
        float es[4], ep[4];
        bool val[4];
        float mxs = -3.0e38f, mxp = -3.0e38f;
#pragma unroll
        for (int q = 0; q < 4; ++q) {
            int j = lane + 64 * q;
            bool vv = false;
            float e1 = -3.0e38f, e2 = -3.0e38f;
            if (j < 200) {
                unsigned int mw = maskw[(size_t)(b * 200 + i) * 8 + (j >> 5)];
                vv = (mw >> (j & 31)) & 1u;
                if (vv) {
                    float x1 = s1sv + s2s[j]; e1 = x1 >= 0.f ? x1 : 0.3f * x1;
                    float x2 = s1pv + s2p[j]; e2 = x2 >= 0.f ? x2 : 0.3f * x2;
                    mxs = fmaxf(mxs, e1);
                    mxp = fmaxf(mxp, e2);
                }
            }
            val[q] = vv; es[q] = e1; ep[q] = e2;
        }
        for (int off = 32; off; off >>= 1) {
            mxs = fmaxf(mxs, __shfl_xor(mxs, off, 64));
            mxp = fmaxf(mxp, __shfl_xor(mxp, off, 64));
        }
        float ds = 0.f, dp = 0.f, pa0 = 0.f, pa1 = 0.f, pb0 = 0.f, pb1 = 0.f;
#pragma unroll
        for (int q = 0; q < 4; ++q) {
            if (!val[q]) continue;
            int j = lane + 64 * q;
            float p1 = __expf(es[q] - mxs), p2 = __expf(ep[q] - mxp);
            ds += p1; dp += p2;
            float4 hv = *(float4*)&hsp[j * 4];
            pa0 += p1 * hv.x; pa1 += p1 * hv.y;
            pb0 += p2 * hv.z; pb1 += p2 * hv.w;
        }
        for (int off = 32; off; off >>= 1) {
            ds  += __shfl_xor(ds, off, 64);  dp  += __shfl_xor(dp, off, 64);
            pa0 += __shfl_xor(pa0, off, 64); pa1 += __shfl_xor(pa1, off, 64);
            pb0 += __shfl_xor(pb0, off, 64); pb1 += __shfl_xor(pb1, off, 64);
        }
        if (lane == 0) {
            float gs = BN_SCALEF * bns_g[i], bs = bns_b[i];
            float v0 = (pa0 / ds) * gs + bs, v1 = (pa1 / ds) * gs + bs;
            out[(size_t)(b * 200 + i) * 2 + 0] = 1.f / (1.f + __expf(-v0));
            out[(size_t)(b * 200 + i) * 2 + 1] = 1.f / (1.f + __expf(-v1));
            float gp = BN_SCALEF * bnp_g[i], bp = bnp_b[i];
            float u0 = (pb0 / dp) * gp + bp, u1 = (pb1 / dp) * gp + bp;
            out[51200 + (size_t)(b * 200 + i) * 2 + 0] = u0 > 0.f ? u0 : __expf(u0) - 1.f;
            out[51200 + (size_t)(b * 200 + i) * 2 + 1] = u1 > 0.f ? u1 : __expf(u1) - 1.f;
        }
    }
}

// ---------------------------------------------------------------- q attention (row 0 only) + W2 + ELU

__global__ __launch_bounds__(256) void attn_q(const float* __restrict__ H2,
                                              const float* __restrict__ sv,
                                              const unsigned int* __restrict__ maskw,
                                              const float* __restrict__ bnq_g, const float* __restrict__ bnq_b,
                                              const float* __restrict__ W2, float* __restrict__ out) {
    __shared__ float p_lds[200];
    __shared__ float redm[4], redd[4];
    __shared__ float red2[256];
    int b = blockIdx.x, t = threadIdx.x;
    float s1v = sv[102400 + b * 200];
    bool v = false;
    float e = -3.0e38f;
    if (t < 200) {
        unsigned int mw = maskw[(size_t)(b * 200) * 8 + (t >> 5)];
        v = (mw >> (t & 31)) & 1u;
        if (v) {
            float x = s1v + sv[128000 + b * 200 + t];
            e = x >= 0.f ? x : 0.3f * x;
        }
    }
    float mx = e;
    for (int off = 32; off; off >>= 1) mx = fmaxf(mx, __shfl_xor(mx, off, 64));
    if ((t & 63) == 0) redm[t >> 6] = mx;
    __syncthreads();
    mx = fmaxf(fmaxf(redm[0], redm[1]), fmaxf(redm[2], redm[3]));
    float p = v ? __expf(e - mx) : 0.f;
    if (t < 200) p_lds[t] = p;
    float ds = p;
    for (int off = 32; off; off >>= 1) ds += __shfl_xor(ds, off, 64);
    if ((t & 63) == 0) redd[t >> 6] = ds;
    __syncthreads();
    ds = redd[0] + redd[1] + redd[2] + redd[3];
    int o = t & 31, g = t >> 5;
    float acc = 0.f;
    for (int j = g; j < 200; j += 8)
        acc += p_lds[j] * H2[(size_t)(b * 200 + j) * 36 + 4 + o];
    red2[t] = acc;
    __syncthreads();
    if (t < 32) {
        float s = 0.f;
#pragma unroll
        for (int gg = 0; gg < 8; ++gg) s += red2[gg * 32 + t];
        float qv = (s / ds) * (BN_SCALEF * bnq_g[0]) + bnq_b[0];  // node 0, no ELU (concat=False)
        float c0 = qv * W2[t * 2], c1 = qv * W2[t * 2 + 1];
#pragma unroll
        for (int off = 16; off; off >>= 1) {
            c0 += __shfl_xor(c0, off, 64);
            c1 += __shfl_xor(c1, off, 64);
        }
        if (t == 0) {
            out[102400 + b * 2 + 0] = c0 > 0.f ? c0 : __expf(c0) - 1.f;
            out[102400 + b * 2 + 1] = c1 > 0.f ? c1 : __expf(c1) - 1.f;
        }
    }
}

// ---------------------------------------------------------------- launch

extern "C" void kernel_launch(void* const* d_in, const int* in_sizes, int n_in,
                              void* d_out, int out_size, void* d_ws, size_t ws_size,
                              hipStream_t stream) {
    (void)in_sizes; (void)n_in; (void)out_size; (void)ws_size;
    const float* feat    = (const float*)d_in[0];
    const int*   adj     = (const int*)d_in[1];
    const float* W_heads = (const float*)d_in[2];
    const float* a_heads = (const float*)d_in[3];
    const float* bnh_g   = (const float*)d_in[4];
    const float* bnh_b   = (const float*)d_in[5];
    const float* bnt_g   = (const float*)d_in[6];
    const float* bnt_b   = (const float*)d_in[7];
    const float* W_sent  = (const float*)d_in[8];
    const float* a_sent  = (const float*)d_in[9];
    const float* bns_g   = (const float*)d_in[10];
    const float* bns_b   = (const float*)d_in[11];
    const float* W_para  = (const float*)d_in[12];
    const float* a_para  = (const float*)d_in[13];
    const float* bnp_g   = (const float*)d_in[14];
    const float* bnp_b   = (const float*)d_in[15];
    const float* W_q     = (const float*)d_in[16];
    const float* a_q     = (const float*)d_in[17];
    const float* bnq_g   = (const float*)d_in[18];
    const float* bnq_b   = (const float*)d_in[19];
    const float* W2      = (const float*)d_in[20];
    float* out = (float*)d_out;
    float* ws  = (float*)d_ws;

    float* h_all = ws;                          // 6,553,600 f
    float* x_cat = ws + 6553600;                // 6,553,600 f
    float* s1h   = ws + 13107200;               // 204,800 f
    float* s2h   = ws + 13312000;               // 204,800 f
    float* w2t   = ws + 13516800;               // 9,216 f
    _Float16* Bt = (_Float16*)(ws + 13526016);  // 196,608 h (= 98,304 f)
    unsigned int* maskw = (unsigned int*)(ws + 13624320);  // 204,800 words
    float* h2    = ws + 13829120;               // 921,600 f
    float* sv    = ws + 14750720;               // 153,600 f (end ~59.6 MB)

    pack_mask<<<dim3(25600), dim3(256), 0, stream>>>(adj, maskw);
    build_wcat_t<<<dim3(256), dim3(256), 0, stream>>>(W_heads, Bt);
    build_w2t<<<dim3(36), dim3(256), 0, stream>>>(W_sent, W_para, W_q, w2t);
    gemm1_mfma<<<dim3(200), dim3(512), 0, stream>>>(feat, Bt, a_heads, h_all, s1h, s2h);
    attn_heads<<<dim3(1024), dim3(256), 0, stream>>>(h_all, s1h, s2h, maskw,
                                                     bnh_g, bnh_b, bnt_g, bnt_b, x_cat);
    gemm2<<<dim3(200), dim3(256), 0, stream>>>(x_cat, w2t, h2);
    s12_second<<<dim3(100), dim3(256), 0, stream>>>(h2, a_sent, a_para, a_q, sv);
    attn_sp<<<dim3(128, 2), dim3(256), 0, stream>>>(h2, sv, maskw, bns_g, bns_b,
                                                    bnp_g, bnp_b, out);
    attn_q<<<dim3(128), dim3(256), 0, stream>>>(h2, sv, maskw, bnq_g, bnq_b, W2, out);
}

// Round 3
// 318.010 us; speedup vs baseline: 1.8741x; 1.4335x over previous
//
#include <hip/hip_runtime.h>
#include <hip/hip_bf16.h>
#include <cstdint>

#define BN_SCALEF 0.99999500003749975f  // 1/sqrt(1+1e-5)
#define EXP_SHIFT 4.0f

// Problem constants: B=128, N=200, F=768, H=8, Fo=32, Fh=256

typedef _Float16 half8 __attribute__((ext_vector_type(8)));
typedef _Float16 half4 __attribute__((ext_vector_type(4)));
typedef float floatx4 __attribute__((ext_vector_type(4)));

// ---------------------------------------------------------------- prep kernels

__global__ void pack_mask(const int* __restrict__ adj, unsigned int* __restrict__ maskw) {
    int bi = blockIdx.x;            // b*200 + i, 25600 blocks
    int t  = threadIdx.x;           // 256
    bool v = false;
    if (t < 200) v = adj[(size_t)bi * 200 + t] > 0;
    unsigned long long m = __ballot(v ? 1 : 0);
    if ((t & 63) == 0) {
        maskw[bi * 8 + (t >> 6) * 2 + 0] = (unsigned int)(m & 0xffffffffULL);
        maskw[bi * 8 + (t >> 6) * 2 + 1] = (unsigned int)(m >> 32);
    }
}

// Wcat^T in f16: Bt[c][f], c = h*32+o
__global__ void build_wcat_t(const float* __restrict__ W_heads, _Float16* __restrict__ Bt) {
    int c = blockIdx.x;   // 256
    int h = c >> 5, o = c & 31;
    for (int f = threadIdx.x; f < 768; f += 256)
        Bt[(size_t)c * 768 + f] = (_Float16)W_heads[h * (768 * 32) + f * 32 + o];
}

__global__ void build_w2t(const float* __restrict__ Ws, const float* __restrict__ Wp,
                          const float* __restrict__ Wq, float* __restrict__ W2t) {
    int c = blockIdx.x;   // 36
    int k = threadIdx.x;  // 256
    float v;
    if (c < 2)      v = Ws[k * 2 + c];
    else if (c < 4) v = Wp[k * 2 + (c - 2)];
    else            v = Wq[k * 32 + (c - 4)];
    W2t[c * 256 + k] = v;
}

// ---------------------------------------------------------------- GEMM1 (f16 MFMA) + fused s1/s2

__global__ __launch_bounds__(512) void gemm1_mfma(const float* __restrict__ A,
                                                  const _Float16* __restrict__ Bt,
                                                  const float* __restrict__ a_h,
                                                  float* __restrict__ C,
                                                  float* __restrict__ s1,
                                                  float* __restrict__ s2) {
    __shared__ __align__(16) _Float16 As[128 * 40];   // [row][k], stride 40 (pad 8)
    __shared__ __align__(16) _Float16 Bs[256 * 40];   // [col][k], stride 40
    int t = threadIdx.x;
    int m0 = blockIdx.x * 128;
    int w = t >> 6, lane = t & 63;
    int wr = w >> 2, wc = w & 3;            // wave 2x4 over (row, col)
    int quad = lane >> 4, l16 = lane & 15;

    floatx4 acc[4][4];
#pragma unroll
    for (int i = 0; i < 4; ++i)
#pragma unroll
        for (int j = 0; j < 4; ++j) acc[i][j] = (floatx4){0.f, 0.f, 0.f, 0.f};

    int arow = t >> 2, akoff = (t & 3) * 8;      // A: 128 rows x 32 k
    int bcol = t >> 1, bkoff = (t & 1) * 16;     // B: 256 cols x 32 k
    const float*    Aptr = &A[(size_t)(m0 + arow) * 768 + akoff];
    const _Float16* Bptr = &Bt[(size_t)bcol * 768 + bkoff];

    float4 pa0 = *(const float4*)(Aptr);
    float4 pa1 = *(const float4*)(Aptr + 4);
    uint4  pb0 = *(const uint4*)(Bptr);
    uint4  pb1 = *(const uint4*)(Bptr + 8);

    for (int k0 = 0; k0 < 768; k0 += 32) {
        half8 ah;
        ah[0] = (_Float16)pa0.x; ah[1] = (_Float16)pa0.y;
        ah[2] = (_Float16)pa0.z; ah[3] = (_Float16)pa0.w;
        ah[4] = (_Float16)pa1.x; ah[5] = (_Float16)pa1.y;
        ah[6] = (_Float16)pa1.z; ah[7] = (_Float16)pa1.w;
        *(half8*)&As[arow * 40 + akoff] = ah;
        *(uint4*)&Bs[bcol * 40 + bkoff]     = pb0;
        *(uint4*)&Bs[bcol * 40 + bkoff + 8] = pb1;
        __syncthreads();
        if (k0 + 32 < 768) {
            pa0 = *(const float4*)(Aptr + k0 + 32);
            pa1 = *(const float4*)(Aptr + k0 + 36);
            pb0 = *(const uint4*)(Bptr + k0 + 32);
            pb1 = *(const uint4*)(Bptr + k0 + 40);
        }
        half8 af[4], bf[4];
#pragma unroll
        for (int rt = 0; rt < 4; ++rt)
            af[rt] = *(half8*)&As[(wr * 64 + rt * 16 + l16) * 40 + quad * 8];
#pragma unroll
        for (int ct = 0; ct < 4; ++ct)
            bf[ct] = *(half8*)&Bs[(wc * 64 + ct * 16 + l16) * 40 + quad * 8];
#pragma unroll
        for (int rt = 0; rt < 4; ++rt)
#pragma unroll
            for (int ct = 0; ct < 4; ++ct)
                acc[rt][ct] = __builtin_amdgcn_mfma_f32_16x16x32_f16(af[rt], bf[ct], acc[rt][ct], 0, 0, 0);
        __syncthreads();
    }

    int rbase = m0 + wr * 64;
    int cbase = wc * 64;
#pragma unroll
    for (int rt = 0; rt < 4; ++rt)
#pragma unroll
        for (int ct = 0; ct < 4; ++ct) {
            int gc = cbase + ct * 16 + l16;
#pragma unroll
            for (int r = 0; r < 4; ++r) {
                int gr = rbase + rt * 16 + quad * 4 + r;
                C[(size_t)gr * 256 + gc] = acc[rt][ct][r];
            }
        }
#pragma unroll
    for (int hh = 0; hh < 2; ++hh) {
        int h0 = wc * 2 + hh;
        const float* ab = &a_h[h0 * 64];
        float a1l = ab[l16], a1h = ab[16 + l16];
        float a2l = ab[32 + l16], a2h = ab[48 + l16];
#pragma unroll
        for (int rt = 0; rt < 4; ++rt)
#pragma unroll
            for (int r = 0; r < 4; ++r) {
                float v0 = acc[rt][2 * hh][r], v1 = acc[rt][2 * hh + 1][r];
                float p1 = v0 * a1l + v1 * a1h;
                float p2 = v0 * a2l + v1 * a2h;
                p1 += __shfl_xor(p1, 1, 64); p1 += __shfl_xor(p1, 2, 64);
                p1 += __shfl_xor(p1, 4, 64); p1 += __shfl_xor(p1, 8, 64);
                p2 += __shfl_xor(p2, 1, 64); p2 += __shfl_xor(p2, 2, 64);
                p2 += __shfl_xor(p2, 4, 64); p2 += __shfl_xor(p2, 8, 64);
                if (l16 == 0) {
                    int gr = rbase + rt * 16 + quad * 4 + r;
                    s1[h0 * 25600 + gr] = p1;
                    s2[h0 * 25600 + gr] = p2;
                }
            }
    }
}

// ---------------------------------------------------------------- head attention via MFMA
// Per block (h,b). P[200x200] f16 (normalized-free exp(e-4)); PV and row-sums
// via mfma_f32_16x16x32_f16 with a ones-column appended to the h-tile (N=33).
// Waves own private 16-row P slabs -> no barriers in the main loop.

__global__ __launch_bounds__(256) void attn_heads_mfma(
    const float* __restrict__ h_all, const float* __restrict__ s1g, const float* __restrict__ s2g,
    const unsigned int* __restrict__ maskw,
    const float* __restrict__ bnh_g, const float* __restrict__ bnh_b,
    const float* __restrict__ bnt_g, const float* __restrict__ bnt_b,
    float* __restrict__ x_cat) {
    __shared__ __align__(16) _Float16 Bs[48 * 232];   // [n][k]: n<32 h^T, n=32 ones, rest 0
    __shared__ __align__(16) _Float16 Ps[64 * 232];   // 4 waves x 16-row slabs
    int hb = blockIdx.x;
    int h = hb >> 7, b = hb & 127;
    int t = threadIdx.x;

    // zero Bs (covers k-pad and n=33..47)
    unsigned long long* bz = (unsigned long long*)Bs;
    for (int idx = t; idx < (48 * 232) / 4; idx += 256) bz[idx] = 0ULL;
    __syncthreads();
    // fill h^T (f16) + ones column
    for (int idx = t; idx < 1600; idx += 256) {
        int j = idx >> 3, w4 = (idx & 7) * 4;
        float4 v = *(const float4*)&h_all[(size_t)(b * 200 + j) * 256 + h * 32 + w4];
        Bs[(w4 + 0) * 232 + j] = (_Float16)v.x;
        Bs[(w4 + 1) * 232 + j] = (_Float16)v.y;
        Bs[(w4 + 2) * 232 + j] = (_Float16)v.z;
        Bs[(w4 + 3) * 232 + j] = (_Float16)v.w;
    }
    if (t < 200) Bs[32 * 232 + t] = (_Float16)1.0f;
    __syncthreads();

    int w = t >> 6, lane = t & 63;
    int l16 = lane & 15, quad = lane >> 4;
    _Float16* Pw = &Ps[w * 16 * 232];

    // per-lane constants: j = 4*lane + q  (j in [0,256))
    int j0 = lane * 4;
    float4 s2r = {0.f, 0.f, 0.f, 0.f};
    if (j0 + 3 < 200) {
        s2r = *(const float4*)&s2g[(size_t)(h * 128 + b) * 200 + j0];
    } else if (j0 < 200) {
        const float* sp = &s2g[(size_t)(h * 128 + b) * 200];
        float tmp[4] = {0.f, 0.f, 0.f, 0.f};
        for (int q = 0; q < 4 && j0 + q < 200; ++q) tmp[q] = sp[j0 + q];
        s2r = {tmp[0], tmp[1], tmp[2], tmp[3]};
    }
    const float* s1p = &s1g[(size_t)(h * 128 + b) * 200];

    for (int tile = w; tile < 13; tile += 4) {
        int i_base = tile * 16;
        int nrows = (i_base + 16 <= 200) ? 16 : (200 - i_base);
        // ---- softmax phase: p = mask ? exp(e - 4) : 0, f16, unnormalized
        for (int r16 = 0; r16 < nrows; ++r16) {
            int i = i_base + r16;
            float s1v = s1p[i];
            unsigned int mw = maskw[(size_t)(b * 200 + i) * 8 + (lane >> 3)];
            half4 pv;
#pragma unroll
            for (int q = 0; q < 4; ++q) {
                float e = s1v + ((const float*)&s2r)[q];
                e = fmaxf(e, 0.3f * e);                    // leaky relu
                float p = ((mw >> ((j0 + q) & 31)) & 1u) ? __expf(e - EXP_SHIFT) : 0.f;
                pv[q] = (_Float16)p;
            }
            if (j0 < 224) *(half4*)&Pw[r16 * 232 + j0] = pv;
        }
        // ---- MFMA phase: C[16x33] = P_tile @ [h | 1]
        floatx4 acc0 = {0.f, 0.f, 0.f, 0.f};
        floatx4 acc1 = {0.f, 0.f, 0.f, 0.f};
        floatx4 acc2 = {0.f, 0.f, 0.f, 0.f};
#pragma unroll
        for (int kt = 0; kt < 7; ++kt) {
            half8 af = *(half8*)&Pw[l16 * 232 + kt * 32 + quad * 8];
            half8 b0 = *(half8*)&Bs[(l16) * 232 + kt * 32 + quad * 8];
            half8 b1 = *(half8*)&Bs[(16 + l16) * 232 + kt * 32 + quad * 8];
            half8 b2 = *(half8*)&Bs[(32 + l16) * 232 + kt * 32 + quad * 8];
            acc0 = __builtin_amdgcn_mfma_f32_16x16x32_f16(af, b0, acc0, 0, 0, 0);
            acc1 = __builtin_amdgcn_mfma_f32_16x16x32_f16(af, b1, acc1, 0, 0, 0);
            acc2 = __builtin_amdgcn_mfma_f32_16x16x32_f16(af, b2, acc2, 0, 0, 0);
        }
        // ---- epilogue: normalize by MFMA row-sum, BN + ELU + top BN
#pragma unroll
        for (int r = 0; r < 4; ++r) {
            int i = i_base + quad * 4 + r;
            float rsum = __shfl(acc2[r], (lane & 48), 64);   // col 32 lives in lane quad*16
            if (i < 200) {
                float inv = 1.f / rsum;
                float g1 = BN_SCALEF * bnh_g[h * 200 + i], c1 = bnh_b[h * 200 + i];
                float g2 = BN_SCALEF * bnt_g[i], c2 = bnt_b[i];
                float v0 = acc0[r] * inv * g1 + c1;
                v0 = v0 > 0.f ? v0 : __expf(v0) - 1.f;
                v0 = v0 * g2 + c2;
                float v1 = acc1[r] * inv * g1 + c1;
                v1 = v1 > 0.f ? v1 : __expf(v1) - 1.f;
                v1 = v1 * g2 + c2;
                size_t base = (size_t)(b * 200 + i) * 256 + h * 32;
                x_cat[base + l16]      = v0;
                x_cat[base + 16 + l16] = v1;
            }
        }
    }
}

// ---------------------------------------------------------------- GEMM2: h2 = x_cat @ W2t^T  (36 cols)

__global__ __launch_bounds__(256) void gemm2(const float* __restrict__ X,
                                             const float* __restrict__ W2t,
                                             float* __restrict__ H2) {
    __shared__ __align__(16) float Ws[36 * 260];
    int t = threadIdx.x;
#pragma unroll
    for (int rep = 0; rep < 9; ++rep) {
        int fidx = rep * 1024 + t * 4;
        int c = fidx >> 8, k = fidx & 255;
        *(float4*)&Ws[c * 260 + k] = *(const float4*)&W2t[fidx];
    }
    __syncthreads();
    int cg = t & 3, rt = t >> 2;
    int row0 = blockIdx.x * 128 + rt * 2;
    float acc[2][9] = {};
#pragma unroll 2
    for (int k = 0; k < 256; k += 4) {
        float4 x0 = *(const float4*)&X[(size_t)row0 * 256 + k];
        float4 x1 = *(const float4*)&X[(size_t)(row0 + 1) * 256 + k];
#pragma unroll
        for (int c = 0; c < 9; ++c) {
            float4 wv = *(float4*)&Ws[(cg * 9 + c) * 260 + k];
            acc[0][c] += x0.x * wv.x + x0.y * wv.y + x0.z * wv.z + x0.w * wv.w;
            acc[1][c] += x1.x * wv.x + x1.y * wv.y + x1.z * wv.z + x1.w * wv.w;
        }
    }
#pragma unroll
    for (int rr = 0; rr < 2; ++rr)
#pragma unroll
        for (int c = 0; c < 9; ++c)
            H2[(size_t)(row0 + rr) * 36 + cg * 9 + c] = acc[rr][c];
}

// ---------------------------------------------------------------- s1/s2 for sent/para/q

__global__ __launch_bounds__(256) void s12_second(const float* __restrict__ H2,
                                                  const float* __restrict__ a_sent,
                                                  const float* __restrict__ a_para,
                                                  const float* __restrict__ a_q,
                                                  float* __restrict__ sv) {
    int row = blockIdx.x * 256 + threadIdx.x;  // 25600
    const float* hp = &H2[(size_t)row * 36];
    float h0 = hp[0], h1 = hp[1], h2v = hp[2], h3 = hp[3];
    sv[row]          = h0 * a_sent[0] + h1 * a_sent[1];
    sv[25600 + row]  = h0 * a_sent[2] + h1 * a_sent[3];
    sv[51200 + row]  = h2v * a_para[0] + h3 * a_para[1];
    sv[76800 + row]  = h2v * a_para[2] + h3 * a_para[3];
    float aq1 = 0.f, aq2 = 0.f;
#pragma unroll
    for (int o = 0; o < 32; ++o) {
        float hv = hp[4 + o];
        aq1 += hv * a_q[o];
        aq2 += hv * a_q[32 + o];
    }
    sv[102400 + row] = aq1;
    sv[128000 + row] = aq2;
}

// ---------------------------------------------------------------- sent+para attention (Fo=2 each), wave-per-row

__global__ __launch_bounds__(256) void attn_sp(const float* __restrict__ H2,
                                               const float* __restrict__ sv,
                                               const unsigned int* __restrict__ maskw,
                                               const float* __restrict__ bns_g, const float* __restrict__ bns_b,
                                               const float* __restrict__ bnp_g, const float* __restrict__ bnp_b,
                                               float* __restrict__ out) {
    __shared__ float s2s[200], s2p[200];
    __shared__ __align__(16) float hsp[200 * 4];
    int b = blockIdx.x, chunk = blockIdx.y;
    int t = threadIdx.x;
    if (t < 200) {
        s2s[t] = sv[25600 + b * 200 + t];
        s2p[t] = sv[76800 + b * 200 + t];
    }
    for (int idx = t; idx < 800; idx += 256) {
        int j = idx >> 2, c = idx & 3;
        hsp[idx] = H2[(size_t)(b * 200 + j) * 36 + c];
    }
    __syncthreads();
    int w = t >> 6, lane = t & 63;
    for (int it = 0; it < 25; ++it) {
        int i = chunk * 100 + it * 4 + w;
        float s1sv = sv[b * 200 + i];
        float s1pv = sv[51200 + b * 200 + i];
        float ds = 0.f, dp = 0.f, pa0 = 0.f, pa1 = 0.f, pb0 = 0.f, pb1 = 0.f;
#pragma unroll
        for (int q = 0; q < 4; ++q) {
            int j = lane + 64 * q;
            if (j < 200) {
                unsigned int mw = maskw[(size_t)(b * 200 + i) * 8 + (j >> 5)];
                if ((mw >> (j & 31)) & 1u) {
                    float x1 = s1sv + s2s[j]; x1 = fmaxf(x1, 0.3f * x1);
                    float x2 = s1pv + s2p[j]; x2 = fmaxf(x2, 0.3f * x2);
                    float p1 = __expf(x1 - EXP_SHIFT), p2 = __expf(x2 - EXP_SHIFT);
                    ds += p1; dp += p2;
                    float4 hv = *(float4*)&hsp[j * 4];
                    pa0 += p1 * hv.x; pa1 += p1 * hv.y;
                    pb0 += p2 * hv.z; pb1 += p2 * hv.w;
                }
            }
        }
        for (int off = 32; off; off >>= 1) {
            ds  += __shfl_xor(ds, off, 64);  dp  += __shfl_xor(dp, off, 64);
            pa0 += __shfl_xor(pa0, off, 64); pa1 += __shfl_xor(pa1, off, 64);
            pb0 += __shfl_xor(pb0, off, 64); pb1 += __shfl_xor(pb1, off, 64);
        }
        if (lane == 0) {
            float gs = BN_SCALEF * bns_g[i], bs = bns_b[i];
            float v0 = (pa0 / ds) * gs + bs, v1 = (pa1 / ds) * gs + bs;
            out[(size_t)(b * 200 + i) * 2 + 0] = 1.f / (1.f + __expf(-v0));
            out[(size_t)(b * 200 + i) * 2 + 1] = 1.f / (1.f + __expf(-v1));
            float gp = BN_SCALEF * bnp_g[i], bp = bnp_b[i];
            float u0 = (pb0 / dp) * gp + bp, u1 = (pb1 / dp) * gp + bp;
            out[51200 + (size_t)(b * 200 + i) * 2 + 0] = u0 > 0.f ? u0 : __expf(u0) - 1.f;
            out[51200 + (size_t)(b * 200 + i) * 2 + 1] = u1 > 0.f ? u1 : __expf(u1) - 1.f;
        }
    }
}

// ---------------------------------------------------------------- q attention (row 0 only) + W2 + ELU

__global__ __launch_bounds__(256) void attn_q(const float* __restrict__ H2,
                                              const float* __restrict__ sv,
                                              const unsigned int* __restrict__ maskw,
                                              const float* __restrict__ bnq_g, const float* __restrict__ bnq_b,
                                              const float* __restrict__ W2, float* __restrict__ out) {
    __shared__ float p_lds[200];
    __shared__ float redd[4];
    __shared__ float red2[256];
    int b = blockIdx.x, t = threadIdx.x;
    float s1v = sv[102400 + b * 200];
    float p = 0.f;
    if (t < 200) {
        unsigned int mw = maskw[(size_t)(b * 200) * 8 + (t >> 5)];
        if ((mw >> (t & 31)) & 1u) {
            float x = s1v + sv[128000 + b * 200 + t];
            x = fmaxf(x, 0.3f * x);
            p = __expf(x - EXP_SHIFT);
        }
        p_lds[t] = p;
    }
    float ds = p;
    for (int off = 32; off; off >>= 1) ds += __shfl_xor(ds, off, 64);
    if ((t & 63) == 0) redd[t >> 6] = ds;
    __syncthreads();
    ds = redd[0] + redd[1] + redd[2] + redd[3];
    int o = t & 31, g = t >> 5;
    float acc = 0.f;
    for (int j = g; j < 200; j += 8)
        acc += p_lds[j] * H2[(size_t)(b * 200 + j) * 36 + 4 + o];
    red2[t] = acc;
    __syncthreads();
    if (t < 32) {
        float s = 0.f;
#pragma unroll
        for (int gg = 0; gg < 8; ++gg) s += red2[gg * 32 + t];
        float qv = (s / ds) * (BN_SCALEF * bnq_g[0]) + bnq_b[0];  // node 0, no ELU (concat=False)
        float c0 = qv * W2[t * 2], c1 = qv * W2[t * 2 + 1];
#pragma unroll
        for (int off = 16; off; off >>= 1) {
            c0 += __shfl_xor(c0, off, 64);
            c1 += __shfl_xor(c1, off, 64);
        }
        if (t == 0) {
            out[102400 + b * 2 + 0] = c0 > 0.f ? c0 : __expf(c0) - 1.f;
            out[102400 + b * 2 + 1] = c1 > 0.f ? c1 : __expf(c1) - 1.f;
        }
    }
}

// ---------------------------------------------------------------- launch

extern "C" void kernel_launch(void* const* d_in, const int* in_sizes, int n_in,
                              void* d_out, int out_size, void* d_ws, size_t ws_size,
                              hipStream_t stream) {
    (void)in_sizes; (void)n_in; (void)out_size; (void)ws_size;
    const float* feat    = (const float*)d_in[0];
    const int*   adj     = (const int*)d_in[1];
    const float* W_heads = (const float*)d_in[2];
    const float* a_heads = (const float*)d_in[3];
    const float* bnh_g   = (const float*)d_in[4];
    const float* bnh_b   = (const float*)d_in[5];
    const float* bnt_g   = (const float*)d_in[6];
    const float* bnt_b   = (const float*)d_in[7];
    const float* W_sent  = (const float*)d_in[8];
    const float* a_sent  = (const float*)d_in[9];
    const float* bns_g   = (const float*)d_in[10];
    const float* bns_b   = (const float*)d_in[11];
    const float* W_para  = (const float*)d_in[12];
    const float* a_para  = (const float*)d_in[13];
    const float* bnp_g   = (const float*)d_in[14];
    const float* bnp_b   = (const float*)d_in[15];
    const float* W_q     = (const float*)d_in[16];
    const float* a_q     = (const float*)d_in[17];
    const float* bnq_g   = (const float*)d_in[18];
    const float* bnq_b   = (const float*)d_in[19];
    const float* W2      = (const float*)d_in[20];
    float* out = (float*)d_out;
    float* ws  = (float*)d_ws;

    float* h_all = ws;                          // 6,553,600 f
    float* x_cat = ws + 6553600;                // 6,553,600 f
    float* s1h   = ws + 13107200;               // 204,800 f
    float* s2h   = ws + 13312000;               // 204,800 f
    float* w2t   = ws + 13516800;               // 9,216 f
    _Float16* Bt = (_Float16*)(ws + 13526016);  // 196,608 h (= 98,304 f)
    unsigned int* maskw = (unsigned int*)(ws + 13624320);  // 204,800 words
    float* h2    = ws + 13829120;               // 921,600 f
    float* sv    = ws + 14750720;               // 153,600 f (end ~59.6 MB)

    pack_mask<<<dim3(25600), dim3(256), 0, stream>>>(adj, maskw);
    build_wcat_t<<<dim3(256), dim3(256), 0, stream>>>(W_heads, Bt);
    build_w2t<<<dim3(36), dim3(256), 0, stream>>>(W_sent, W_para, W_q, w2t);
    gemm1_mfma<<<dim3(200), dim3(512), 0, stream>>>(feat, Bt, a_heads, h_all, s1h, s2h);
    attn_heads_mfma<<<dim3(1024), dim3(256), 0, stream>>>(h_all, s1h, s2h, maskw,
                                                          bnh_g, bnh_b, bnt_g, bnt_b, x_cat);
    gemm2<<<dim3(200), dim3(256), 0, stream>>>(x_cat, w2t, h2);
    s12_second<<<dim3(100), dim3(256), 0, stream>>>(h2, a_sent, a_para, a_q, sv);
    attn_sp<<<dim3(128, 2), dim3(256), 0, stream>>>(h2, sv, maskw, bns_g, bns_b,
                                                    bnp_g, bnp_b, out);
    attn_q<<<dim3(128), dim3(256), 0, stream>>>(h2, sv, maskw, bnq_g, bnq_b, W2, out);
}

// Round 4
// 299.905 us; speedup vs baseline: 1.9873x; 1.0604x over previous
//
#include <hip/hip_runtime.h>
#include <hip/hip_bf16.h>
#include <cstdint>

#define BN_SCALEF 0.99999500003749975f  // 1/sqrt(1+1e-5)
#define EXP_SHIFT 4.0f

// Problem constants: B=128, N=200, F=768, H=8, Fo=32, Fh=256

typedef _Float16 half8 __attribute__((ext_vector_type(8)));
typedef _Float16 half4 __attribute__((ext_vector_type(4)));
typedef float floatx4 __attribute__((ext_vector_type(4)));

// ---------------------------------------------------------------- prep: pack_mask + Wcat^T + W2t  (one launch)
// blocks 0..1599: mask rows blk*16..+16 ; 1600..1791: Wcat tile; 1792: w2t

__global__ __launch_bounds__(256) void prep(const int* __restrict__ adj,
                                            const float* __restrict__ W_heads,
                                            const float* __restrict__ Ws_in,
                                            const float* __restrict__ Wp_in,
                                            const float* __restrict__ Wq_in,
                                            unsigned int* __restrict__ maskw,
                                            _Float16* __restrict__ Bt,
                                            float* __restrict__ W2t) {
    int blk = blockIdx.x;
    int t = threadIdx.x;
    if (blk < 1600) {
        int w = t >> 6, lane = t & 63;
        for (int task = w; task < 64; task += 4) {
            int r = blk * 16 + (task >> 2);
            int c0 = (task & 3) * 64;
            int j = c0 + lane;
            bool v = (j < 200) && (adj[(size_t)r * 200 + j] > 0);
            unsigned long long m = __ballot(v ? 1 : 0);
            if (lane == 0) {
                maskw[r * 8 + (c0 >> 5)]     = (unsigned int)(m & 0xffffffffULL);
                maskw[r * 8 + (c0 >> 5) + 1] = (unsigned int)(m >> 32);
            }
        }
    } else if (blk < 1792) {
        __shared__ float ld[32][36];
        int blk2 = blk - 1600;          // h = blk2/24, f-tile = blk2%24
        int h = blk2 / 24, f0 = (blk2 % 24) * 32;
        int idx = t * 4;
        int fr = idx >> 5, o0 = idx & 31;
        float4 v = *(const float4*)&W_heads[(size_t)h * 24576 + (size_t)(f0 + fr) * 32 + o0];
        ld[fr][o0] = v.x; ld[fr][o0 + 1] = v.y; ld[fr][o0 + 2] = v.z; ld[fr][o0 + 3] = v.w;
        __syncthreads();
        int o = idx >> 5, fr0 = idx & 31;
        half4 hv;
#pragma unroll
        for (int u = 0; u < 4; ++u) hv[u] = (_Float16)ld[fr0 + u][o];
        *(half4*)&Bt[(size_t)(h * 32 + o) * 768 + f0 + fr0] = hv;
    } else {
        for (int c = 0; c < 36; ++c) {
            float v;
            if (c < 2)      v = Ws_in[t * 2 + c];
            else if (c < 4) v = Wp_in[t * 2 + (c - 2)];
            else            v = Wq_in[t * 32 + (c - 4)];
            W2t[c * 256 + t] = v;
        }
    }
}

// ---------------------------------------------------------------- GEMM1 (f16 MFMA) + fused s1/s2
// h16[25600,256] = A[25600,768] @ Bt^T ; tile 64x256, 512 thr = 8 waves (2x4),
// wave = 2x4 tiles of 16x16, BK=32; grid 400 (>=1.5 blocks/CU)

__global__ __launch_bounds__(512) void gemm1_mfma(const float* __restrict__ A,
                                                  const _Float16* __restrict__ Bt,
                                                  const float* __restrict__ a_h,
                                                  _Float16* __restrict__ h16,
                                                  float* __restrict__ s1,
                                                  float* __restrict__ s2) {
    __shared__ __align__(16) _Float16 As[64 * 40];    // [row][k], pad 8
    __shared__ __align__(16) _Float16 Bs[256 * 40];   // [col][k]
    int t = threadIdx.x;
    int m0 = blockIdx.x * 64;
    int w = t >> 6, lane = t & 63;
    int wr = w >> 2, wc = w & 3;
    int quad = lane >> 4, l16 = lane & 15;

    floatx4 acc[2][4];
#pragma unroll
    for (int i = 0; i < 2; ++i)
#pragma unroll
        for (int j = 0; j < 4; ++j) acc[i][j] = (floatx4){0.f, 0.f, 0.f, 0.f};

    int arow = t >> 3, akoff = (t & 7) * 4;      // A: 64 rows x 32 k, float4 each
    int bcol = t >> 1, bkoff = (t & 1) * 16;     // B: 256 cols x 32 k, 2x uint4
    const float*    Aptr = &A[(size_t)(m0 + arow) * 768 + akoff];
    const _Float16* Bptr = &Bt[(size_t)bcol * 768 + bkoff];

    float4 pa  = *(const float4*)(Aptr);
    uint4  pb0 = *(const uint4*)(Bptr);
    uint4  pb1 = *(const uint4*)(Bptr + 8);

    for (int k0 = 0; k0 < 768; k0 += 32) {
        half4 ah;
        ah[0] = (_Float16)pa.x; ah[1] = (_Float16)pa.y;
        ah[2] = (_Float16)pa.z; ah[3] = (_Float16)pa.w;
        *(half4*)&As[arow * 40 + akoff] = ah;
        *(uint4*)&Bs[bcol * 40 + bkoff]     = pb0;
        *(uint4*)&Bs[bcol * 40 + bkoff + 8] = pb1;
        __syncthreads();
        if (k0 + 32 < 768) {
            pa  = *(const float4*)(Aptr + k0 + 32);
            pb0 = *(const uint4*)(Bptr + k0 + 32);
            pb1 = *(const uint4*)(Bptr + k0 + 40);
        }
        half8 af[2], bf[4];
#pragma unroll
        for (int rt = 0; rt < 2; ++rt)
            af[rt] = *(half8*)&As[(wr * 32 + rt * 16 + l16) * 40 + quad * 8];
#pragma unroll
        for (int ct = 0; ct < 4; ++ct)
            bf[ct] = *(half8*)&Bs[(wc * 64 + ct * 16 + l16) * 40 + quad * 8];
#pragma unroll
        for (int rt = 0; rt < 2; ++rt)
#pragma unroll
            for (int ct = 0; ct < 4; ++ct)
                acc[rt][ct] = __builtin_amdgcn_mfma_f32_16x16x32_f16(af[rt], bf[ct], acc[rt][ct], 0, 0, 0);
        __syncthreads();
    }

    int rbase = m0 + wr * 32;
    int cbase = wc * 64;
#pragma unroll
    for (int rt = 0; rt < 2; ++rt)
#pragma unroll
        for (int ct = 0; ct < 4; ++ct) {
            int gc = cbase + ct * 16 + l16;
#pragma unroll
            for (int r = 0; r < 4; ++r) {
                int gr = rbase + rt * 16 + quad * 4 + r;
                h16[(size_t)gr * 256 + gc] = (_Float16)acc[rt][ct][r];
            }
        }
#pragma unroll
    for (int hh = 0; hh < 2; ++hh) {
        int h0 = wc * 2 + hh;
        const float* ab = &a_h[h0 * 64];
        float a1l = ab[l16], a1h = ab[16 + l16];
        float a2l = ab[32 + l16], a2h = ab[48 + l16];
#pragma unroll
        for (int rt = 0; rt < 2; ++rt)
#pragma unroll
            for (int r = 0; r < 4; ++r) {
                float v0 = acc[rt][2 * hh][r], v1 = acc[rt][2 * hh + 1][r];
                float p1 = v0 * a1l + v1 * a1h;
                float p2 = v0 * a2l + v1 * a2h;
                p1 += __shfl_xor(p1, 1, 64); p1 += __shfl_xor(p1, 2, 64);
                p1 += __shfl_xor(p1, 4, 64); p1 += __shfl_xor(p1, 8, 64);
                p2 += __shfl_xor(p2, 1, 64); p2 += __shfl_xor(p2, 2, 64);
                p2 += __shfl_xor(p2, 4, 64); p2 += __shfl_xor(p2, 8, 64);
                if (l16 == 0) {
                    int gr = rbase + rt * 16 + quad * 4 + r;
                    s1[h0 * 25600 + gr] = p1;
                    s2[h0 * 25600 + gr] = p2;
                }
            }
    }
}

// ---------------------------------------------------------------- head attention via MFMA (h16 in, x16 out)

__global__ __launch_bounds__(256) void attn_heads_mfma(
    const _Float16* __restrict__ h16, const float* __restrict__ s1g, const float* __restrict__ s2g,
    const unsigned int* __restrict__ maskw,
    const float* __restrict__ bnh_g, const float* __restrict__ bnh_b,
    const float* __restrict__ bnt_g, const float* __restrict__ bnt_b,
    _Float16* __restrict__ x16) {
    __shared__ __align__(16) _Float16 Bs[48 * 232];   // [n][k]: n<32 h^T, n=32 ones, rest 0
    __shared__ __align__(16) _Float16 Ps[64 * 232];   // 4 waves x 16-row slabs
    int hb = blockIdx.x;
    int h = hb >> 7, b = hb & 127;
    int t = threadIdx.x;

    unsigned long long* bz = (unsigned long long*)Bs;
    for (int idx = t; idx < (48 * 232) / 4; idx += 256) bz[idx] = 0ULL;
    __syncthreads();
    for (int idx = t; idx < 800; idx += 256) {
        int j = idx >> 2, w8 = (idx & 3) * 8;
        half8 v = *(const half8*)&h16[(size_t)(b * 200 + j) * 256 + h * 32 + w8];
#pragma unroll
        for (int u = 0; u < 8; ++u) Bs[(w8 + u) * 232 + j] = v[u];
    }
    if (t < 200) Bs[32 * 232 + t] = (_Float16)1.0f;
    __syncthreads();

    int w = t >> 6, lane = t & 63;
    int l16 = lane & 15, quad = lane >> 4;
    _Float16* Pw = &Ps[w * 16 * 232];

    int j0 = lane * 4;
    float4 s2r = {0.f, 0.f, 0.f, 0.f};
    if (j0 + 3 < 200) {
        s2r = *(const float4*)&s2g[(size_t)(h * 128 + b) * 200 + j0];
    } else if (j0 < 200) {
        const float* sp = &s2g[(size_t)(h * 128 + b) * 200];
        float tmp[4] = {0.f, 0.f, 0.f, 0.f};
        for (int q = 0; q < 4 && j0 + q < 200; ++q) tmp[q] = sp[j0 + q];
        s2r = {tmp[0], tmp[1], tmp[2], tmp[3]};
    }
    const float* s1p = &s1g[(size_t)(h * 128 + b) * 200];

    for (int tile = w; tile < 13; tile += 4) {
        int i_base = tile * 16;
        int nrows = (i_base + 16 <= 200) ? 16 : (200 - i_base);
        for (int r16 = 0; r16 < nrows; ++r16) {
            int i = i_base + r16;
            float s1v = s1p[i];
            unsigned int mw = maskw[(size_t)(b * 200 + i) * 8 + (lane >> 3)];
            half4 pv;
#pragma unroll
            for (int q = 0; q < 4; ++q) {
                float e = s1v + ((const float*)&s2r)[q];
                e = fmaxf(e, 0.3f * e);
                float p = ((mw >> ((j0 + q) & 31)) & 1u) ? __expf(e - EXP_SHIFT) : 0.f;
                pv[q] = (_Float16)p;
            }
            if (j0 < 224) *(half4*)&Pw[r16 * 232 + j0] = pv;
        }
        floatx4 acc0 = {0.f, 0.f, 0.f, 0.f};
        floatx4 acc1 = {0.f, 0.f, 0.f, 0.f};
        floatx4 acc2 = {0.f, 0.f, 0.f, 0.f};
#pragma unroll
        for (int kt = 0; kt < 7; ++kt) {
            half8 af = *(half8*)&Pw[l16 * 232 + kt * 32 + quad * 8];
            half8 b0 = *(half8*)&Bs[(l16) * 232 + kt * 32 + quad * 8];
            half8 b1 = *(half8*)&Bs[(16 + l16) * 232 + kt * 32 + quad * 8];
            half8 b2 = *(half8*)&Bs[(32 + l16) * 232 + kt * 32 + quad * 8];
            acc0 = __builtin_amdgcn_mfma_f32_16x16x32_f16(af, b0, acc0, 0, 0, 0);
            acc1 = __builtin_amdgcn_mfma_f32_16x16x32_f16(af, b1, acc1, 0, 0, 0);
            acc2 = __builtin_amdgcn_mfma_f32_16x16x32_f16(af, b2, acc2, 0, 0, 0);
        }
#pragma unroll
        for (int r = 0; r < 4; ++r) {
            int i = i_base + quad * 4 + r;
            float rsum = __shfl(acc2[r], (lane & 48), 64);
            if (i < 200) {
                float inv = 1.f / rsum;
                float g1 = BN_SCALEF * bnh_g[h * 200 + i], c1 = bnh_b[h * 200 + i];
                float g2 = BN_SCALEF * bnt_g[i], c2 = bnt_b[i];
                float v0 = acc0[r] * inv * g1 + c1;
                v0 = v0 > 0.f ? v0 : __expf(v0) - 1.f;
                v0 = v0 * g2 + c2;
                float v1 = acc1[r] * inv * g1 + c1;
                v1 = v1 > 0.f ? v1 : __expf(v1) - 1.f;
                v1 = v1 * g2 + c2;
                size_t base = (size_t)(b * 200 + i) * 256 + h * 32;
                x16[base + l16]      = (_Float16)v0;
                x16[base + 16 + l16] = (_Float16)v1;
            }
        }
    }
}

// ---------------------------------------------------------------- GEMM2 (x16 f16 in) + fused s12_second

__global__ __launch_bounds__(256) void gemm2s(const _Float16* __restrict__ X,
                                              const float* __restrict__ W2t,
                                              const float* __restrict__ a_sent,
                                              const float* __restrict__ a_para,
                                              const float* __restrict__ a_q,
                                              float* __restrict__ H2,
                                              float* __restrict__ sv) {
    __shared__ __align__(16) float Ws[36 * 260];
    __shared__ float Hs[128][37];
    int t = threadIdx.x;
#pragma unroll
    for (int rep = 0; rep < 9; ++rep) {
        int fidx = rep * 1024 + t * 4;
        int c = fidx >> 8, k = fidx & 255;
        *(float4*)&Ws[c * 260 + k] = *(const float4*)&W2t[fidx];
    }
    __syncthreads();
    int cg = t & 3, rt = t >> 2;
    int row0 = blockIdx.x * 128 + rt * 2;
    float acc[2][9] = {};
    for (int k = 0; k < 256; k += 8) {
        half8 x0 = *(const half8*)&X[(size_t)row0 * 256 + k];
        half8 x1 = *(const half8*)&X[(size_t)(row0 + 1) * 256 + k];
        float xf0[8], xf1[8];
#pragma unroll
        for (int u = 0; u < 8; ++u) { xf0[u] = (float)x0[u]; xf1[u] = (float)x1[u]; }
#pragma unroll
        for (int c = 0; c < 9; ++c) {
            const float* wr = &Ws[(cg * 9 + c) * 260 + k];
            float4 wa = *(float4*)wr;
            float4 wb = *(float4*)(wr + 4);
            acc[0][c] += xf0[0] * wa.x + xf0[1] * wa.y + xf0[2] * wa.z + xf0[3] * wa.w
                       + xf0[4] * wb.x + xf0[5] * wb.y + xf0[6] * wb.z + xf0[7] * wb.w;
            acc[1][c] += xf1[0] * wa.x + xf1[1] * wa.y + xf1[2] * wa.z + xf1[3] * wa.w
                       + xf1[4] * wb.x + xf1[5] * wb.y + xf1[6] * wb.z + xf1[7] * wb.w;
        }
    }
#pragma unroll
    for (int rr = 0; rr < 2; ++rr)
#pragma unroll
        for (int c = 0; c < 9; ++c) {
            H2[(size_t)(row0 + rr) * 36 + cg * 9 + c] = acc[rr][c];
            Hs[rt * 2 + rr][cg * 9 + c] = acc[rr][c];
        }
    __syncthreads();
    if (t < 128) {
        int row = blockIdx.x * 128 + t;
        float h0 = Hs[t][0], h1 = Hs[t][1], h2v = Hs[t][2], h3 = Hs[t][3];
        sv[row]          = h0 * a_sent[0] + h1 * a_sent[1];
        sv[25600 + row]  = h0 * a_sent[2] + h1 * a_sent[3];
        sv[51200 + row]  = h2v * a_para[0] + h3 * a_para[1];
        sv[76800 + row]  = h2v * a_para[2] + h3 * a_para[3];
        float aq1 = 0.f, aq2 = 0.f;
#pragma unroll
        for (int o = 0; o < 32; ++o) {
            float hv = Hs[t][4 + o];
            aq1 += hv * a_q[o];
            aq2 += hv * a_q[32 + o];
        }
        sv[102400 + row] = aq1;
        sv[128000 + row] = aq2;
    }
}

// ---------------------------------------------------------------- sent+para attention + q attention (grid y: 0,1=sp chunks, 2=q)

__global__ __launch_bounds__(256) void attn_spq(const float* __restrict__ H2,
                                                const float* __restrict__ sv,
                                                const unsigned int* __restrict__ maskw,
                                                const float* __restrict__ bns_g, const float* __restrict__ bns_b,
                                                const float* __restrict__ bnp_g, const float* __restrict__ bnp_b,
                                                const float* __restrict__ bnq_g, const float* __restrict__ bnq_b,
                                                const float* __restrict__ W2, float* __restrict__ out) {
    int b = blockIdx.x;
    int t = threadIdx.x;
    if (blockIdx.y == 2) {
        // ---- q attention (row 0 only) + W2 + ELU
        __shared__ float p_lds[200];
        __shared__ float redd[4];
        __shared__ float red2[256];
        float s1v = sv[102400 + b * 200];
        float p = 0.f;
        if (t < 200) {
            unsigned int mw = maskw[(size_t)(b * 200) * 8 + (t >> 5)];
            if ((mw >> (t & 31)) & 1u) {
                float x = s1v + sv[128000 + b * 200 + t];
                x = fmaxf(x, 0.3f * x);
                p = __expf(x - EXP_SHIFT);
            }
            p_lds[t] = p;
        }
        float ds = p;
        for (int off = 32; off; off >>= 1) ds += __shfl_xor(ds, off, 64);
        if ((t & 63) == 0) redd[t >> 6] = ds;
        __syncthreads();
        ds = redd[0] + redd[1] + redd[2] + redd[3];
        int o = t & 31, g = t >> 5;
        float acc = 0.f;
        for (int j = g; j < 200; j += 8)
            acc += p_lds[j] * H2[(size_t)(b * 200 + j) * 36 + 4 + o];
        red2[t] = acc;
        __syncthreads();
        if (t < 32) {
            float s = 0.f;
#pragma unroll
            for (int gg = 0; gg < 8; ++gg) s += red2[gg * 32 + t];
            float qv = (s / ds) * (BN_SCALEF * bnq_g[0]) + bnq_b[0];
            float c0 = qv * W2[t * 2], c1 = qv * W2[t * 2 + 1];
#pragma unroll
            for (int off = 16; off; off >>= 1) {
                c0 += __shfl_xor(c0, off, 64);
                c1 += __shfl_xor(c1, off, 64);
            }
            if (t == 0) {
                out[102400 + b * 2 + 0] = c0 > 0.f ? c0 : __expf(c0) - 1.f;
                out[102400 + b * 2 + 1] = c1 > 0.f ? c1 : __expf(c1) - 1.f;
            }
        }
        return;
    }
    // ---- sent + para attention, wave-per-row
    __shared__ float s2s[200], s2p[200];
    __shared__ __align__(16) float hsp[200 * 4];
    int chunk = blockIdx.y;
    if (t < 200) {
        s2s[t] = sv[25600 + b * 200 + t];
        s2p[t] = sv[76800 + b * 200 + t];
    }
    for (int idx = t; idx < 800; idx += 256) {
        int j = idx >> 2, c = idx & 3;
        hsp[idx] = H2[(size_t)(b * 200 + j) * 36 + c];
    }
    __syncthreads();
    int w = t >> 6, lane = t & 63;
    for (int it = 0; it < 25; ++it) {
        int i = chunk * 100 + it * 4 + w;
        float s1sv = sv[b * 200 + i];
        float s1pv = sv[51200 + b * 200 + i];
        float ds = 0.f, dp = 0.f, pa0 = 0.f, pa1 = 0.f, pb0 = 0.f, pb1 = 0.f;
#pragma unroll
        for (int q = 0; q < 4; ++q) {
            int j = lane + 64 * q;
            if (j < 200) {
                unsigned int mw = maskw[(size_t)(b * 200 + i) * 8 + (j >> 5)];
                if ((mw >> (j & 31)) & 1u) {
                    float x1 = s1sv + s2s[j]; x1 = fmaxf(x1, 0.3f * x1);
                    float x2 = s1pv + s2p[j]; x2 = fmaxf(x2, 0.3f * x2);
                    float p1 = __expf(x1 - EXP_SHIFT), p2 = __expf(x2 - EXP_SHIFT);
                    ds += p1; dp += p2;
                    float4 hv = *(float4*)&hsp[j * 4];
                    pa0 += p1 * hv.x; pa1 += p1 * hv.y;
                    pb0 += p2 * hv.z; pb1 += p2 * hv.w;
                }
            }
        }
        for (int off = 32; off; off >>= 1) {
            ds  += __shfl_xor(ds, off, 64);  dp  += __shfl_xor(dp, off, 64);
            pa0 += __shfl_xor(pa0, off, 64); pa1 += __shfl_xor(pa1, off, 64);
            pb0 += __shfl_xor(pb0, off, 64); pb1 += __shfl_xor(pb1, off, 64);
        }
        if (lane == 0) {
            float gs = BN_SCALEF * bns_g[i], bs = bns_b[i];
            float v0 = (pa0 / ds) * gs + bs, v1 = (pa1 / ds) * gs + bs;
            out[(size_t)(b * 200 + i) * 2 + 0] = 1.f / (1.f + __expf(-v0));
            out[(size_t)(b * 200 + i) * 2 + 1] = 1.f / (1.f + __expf(-v1));
            float gp = BN_SCALEF * bnp_g[i], bp = bnp_b[i];
            float u0 = (pb0 / dp) * gp + bp, u1 = (pb1 / dp) * gp + bp;
            out[51200 + (size_t)(b * 200 + i) * 2 + 0] = u0 > 0.f ? u0 : __expf(u0) - 1.f;
            out[51200 + (size_t)(b * 200 + i) * 2 + 1] = u1 > 0.f ? u1 : __expf(u1) - 1.f;
        }
    }
}

// ---------------------------------------------------------------- launch

extern "C" void kernel_launch(void* const* d_in, const int* in_sizes, int n_in,
                              void* d_out, int out_size, void* d_ws, size_t ws_size,
                              hipStream_t stream) {
    (void)in_sizes; (void)n_in; (void)out_size; (void)ws_size;
    const float* feat    = (const float*)d_in[0];
    const int*   adj     = (const int*)d_in[1];
    const float* W_heads = (const float*)d_in[2];
    const float* a_heads = (const float*)d_in[3];
    const float* bnh_g   = (const float*)d_in[4];
    const float* bnh_b   = (const float*)d_in[5];
    const float* bnt_g   = (const float*)d_in[6];
    const float* bnt_b   = (const float*)d_in[7];
    const float* W_sent  = (const float*)d_in[8];
    const float* a_sent  = (const float*)d_in[9];
    const float* bns_g   = (const float*)d_in[10];
    const float* bns_b   = (const float*)d_in[11];
    const float* W_para  = (const float*)d_in[12];
    const float* a_para  = (const float*)d_in[13];
    const float* bnp_g   = (const float*)d_in[14];
    const float* bnp_b   = (const float*)d_in[15];
    const float* W_q     = (const float*)d_in[16];
    const float* a_q     = (const float*)d_in[17];
    const float* bnq_g   = (const float*)d_in[18];
    const float* bnq_b   = (const float*)d_in[19];
    const float* W2      = (const float*)d_in[20];
    float* out = (float*)d_out;
    float* ws  = (float*)d_ws;

    _Float16* h16 = (_Float16*)ws;              // 6,553,600 h = 3,276,800 f
    _Float16* x16 = (_Float16*)(ws + 3276800);  // 6,553,600 h
    float* s1h   = ws + 6553600;                // 204,800 f
    float* s2h   = ws + 6758400;                // 204,800 f
    float* w2t   = ws + 6963200;                // 9,216 f
    _Float16* Bt = (_Float16*)(ws + 6972416);   // 196,608 h = 98,304 f
    unsigned int* maskw = (unsigned int*)(ws + 7070720);  // 204,800 words
    float* h2    = ws + 7275520;                // 921,600 f
    float* sv    = ws + 8197120;                // 153,600 f (end ~33.4 MB)

    prep<<<dim3(1793), dim3(256), 0, stream>>>(adj, W_heads, W_sent, W_para, W_q,
                                               maskw, Bt, w2t);
    gemm1_mfma<<<dim3(400), dim3(512), 0, stream>>>(feat, Bt, a_heads, h16, s1h, s2h);
    attn_heads_mfma<<<dim3(1024), dim3(256), 0, stream>>>(h16, s1h, s2h, maskw,
                                                          bnh_g, bnh_b, bnt_g, bnt_b, x16);
    gemm2s<<<dim3(200), dim3(256), 0, stream>>>(x16, w2t, a_sent, a_para, a_q, h2, sv);
    attn_spq<<<dim3(128, 3), dim3(256), 0, stream>>>(h2, sv, maskw, bns_g, bns_b,
                                                     bnp_g, bnp_b, bnq_g, bnq_b, W2, out);
}